// Round 20
// baseline (1068.188 us; speedup 1.0000x reference)
//
#include <hip/hip_runtime.h>
#include <cstddef>
#include <cstdint>

namespace {

constexpr int NBATCH = 8;
constexpr int NPTS = 2048;
constexpr int KNN = 20;

__device__ __forceinline__ float lrelu(float v) { return fmaxf(v, 0.2f * v); }

// ---------- KNN: top-20 neighbors by neg squared distance ----------
// Keys packed into positive doubles: bits = sortable32(dist)<<30 |
// (2047-idx)<<19 -> double order == (exact f32 dist, then smaller index);
// keys unique -> lax.top_k set semantics. Branch-free per-lane sorted top-20
// via the carry-free min/max identity (39 f64 ops, 2-op critical path).
// 512 threads: 8 waves x 4 rows (dot), 16 lanes/row x 128 cand (select).
template <int C>
__global__ __launch_bounds__(512) void knn_kernel(const float* __restrict__ x, int chStride,
                                                  int bStride, int* __restrict__ idxOut) {
  constexpr int CP = (C + 3) & ~3;   // padded channels
  constexpr int MT = 128;            // columns per tile
  constexpr int ROWS = 32;           // rows per block
  constexpr int RPW = 4;             // rows per wave (dot phase)
  constexpr int LPR = 16;            // lanes per row (select phase)
  constexpr int DS = MT + 4;         // dist row stride (132 -> 2-way, free)
  constexpr int NT = NPTS / MT;      // 16 tiles

  __shared__ float qt[ROWS * CP];
  __shared__ float xt[CP * MT];      // column-major: xt[c*MT + m]
  __shared__ float dist[ROWS * DS];

  const int tid = threadIdx.x;
  const int lane = tid & 63;
  const int wv = tid >> 6;           // 0..7
  const int r0 = wv * RPW;
  const int b = blockIdx.x / (NPTS / ROWS);
  const int n0 = (blockIdx.x % (NPTS / ROWS)) * ROWS;
  const float* xb = x + (size_t)b * bStride;

  for (int t = tid; t < ROWS * CP; t += 512) {
    int r = t / CP, c = t % CP;
    qt[r * CP + c] = (c < C) ? xb[(size_t)c * chStride + n0 + r] : 0.f;
  }
  __syncthreads();

  // per-row query self-dot (broadcast LDS reads)
  float xn[RPW];
#pragma unroll
  for (int r = 0; r < RPW; ++r) {
    float s = 0.f;
#pragma unroll
    for (int cb = 0; cb < CP; cb += 4) {
      float4 qv = *(const float4*)&qt[(r0 + r) * CP + cb];
      s = fmaf(qv.x, qv.x, s);
      s = fmaf(qv.y, qv.y, s);
      s = fmaf(qv.z, qv.z, s);
      s = fmaf(qv.w, qv.w, s);
    }
    xn[r] = s;
  }

  // selection state: 16 lanes/row, per-lane sorted-ascending top-20 keys
  const int srow = tid >> 4;         // 0..31
  const int ssub = tid & 15;
  double lv[KNN];
#pragma unroll
  for (int s = 0; s < KNN; ++s) lv[s] = -1.0;  // below all packed keys (>=0)

  // running index-key part: (2047 - gidx) << 19, gidx = mt*128 + j*16 + ssub
  unsigned long long ib = (unsigned long long)(2047 - ssub) << 19;

#pragma unroll 1
  for (int mt = 0; mt < NT; ++mt) {
    __syncthreads();  // all waves done reading xt of previous tile
    {
      const float4 z4 = make_float4(0.f, 0.f, 0.f, 0.f);
      for (int t = tid; t < CP * MT / 4; t += 512) {
        int f = t * 4;
        int c = f >> 7, m = f & (MT - 1);
        *(float4*)&xt[f] =
            (c < C) ? *(const float4*)&xb[(size_t)c * chStride + mt * MT + m] : z4;
      }
    }
    __syncthreads();  // xt ready

    float acc0[RPW], acc1[RPW];
    float xm0 = 0.f, xm1 = 0.f;
#pragma unroll
    for (int r = 0; r < RPW; ++r) { acc0[r] = 0.f; acc1[r] = 0.f; }
#pragma unroll 1
    for (int cb = 0; cb < CP; cb += 4) {
      float x00 = xt[(cb + 0) * MT + lane];
      float x01 = xt[(cb + 1) * MT + lane];
      float x02 = xt[(cb + 2) * MT + lane];
      float x03 = xt[(cb + 3) * MT + lane];
      float x10 = xt[(cb + 0) * MT + 64 + lane];
      float x11 = xt[(cb + 1) * MT + 64 + lane];
      float x12 = xt[(cb + 2) * MT + 64 + lane];
      float x13 = xt[(cb + 3) * MT + 64 + lane];
      xm0 = fmaf(x00, x00, xm0);
      xm0 = fmaf(x01, x01, xm0);
      xm0 = fmaf(x02, x02, xm0);
      xm0 = fmaf(x03, x03, xm0);
      xm1 = fmaf(x10, x10, xm1);
      xm1 = fmaf(x11, x11, xm1);
      xm1 = fmaf(x12, x12, xm1);
      xm1 = fmaf(x13, x13, xm1);
#pragma unroll
      for (int r = 0; r < RPW; ++r) {
        float4 qv = *(const float4*)&qt[(r0 + r) * CP + cb];
        acc0[r] = fmaf(qv.x, x00, acc0[r]);
        acc0[r] = fmaf(qv.y, x01, acc0[r]);
        acc0[r] = fmaf(qv.z, x02, acc0[r]);
        acc0[r] = fmaf(qv.w, x03, acc0[r]);
        acc1[r] = fmaf(qv.x, x10, acc1[r]);
        acc1[r] = fmaf(qv.y, x11, acc1[r]);
        acc1[r] = fmaf(qv.z, x12, acc1[r]);
        acc1[r] = fmaf(qv.w, x13, acc1[r]);
      }
    }
#pragma unroll
    for (int r = 0; r < RPW; ++r) {
      dist[(r0 + r) * DS + lane] = 2.f * acc0[r] - xn[r] - xm0;
      dist[(r0 + r) * DS + 64 + lane] = 2.f * acc1[r] - xn[r] - xm1;
    }
    // rows r0..r0+3 are read below by lanes of this same wave -> no barrier

    // per-lane: pack candidate into key, branch-free sorted insert
#pragma unroll
    for (int j = 0; j < MT / LPR; ++j) {
      float val = dist[srow * DS + j * LPR + ssub];
      unsigned int u = __float_as_uint(val);
      u ^= (unsigned int)(((int)u) >> 31) | 0x80000000u;
      double kd = __longlong_as_double((long long)(((unsigned long long)u << 30) | ib));
      ib -= (unsigned long long)LPR << 19;
#pragma unroll
      for (int s = 0; s < KNN - 1; ++s) lv[s] = fmin(lv[s + 1], fmax(lv[s], kd));
      lv[KNN - 1] = fmax(lv[KNN - 1], kd);
    }
  }

  // merge 16 lanes' lists per row: keys unique -> single-owner pop per round
  int* op = idxOut + ((size_t)b * NPTS + n0 + srow) * KNN;
#pragma unroll 1
  for (int round = 0; round < KNN; ++round) {
    double bv = lv[KNN - 1];
    bv = fmax(bv, __shfl_xor(bv, 1));
    bv = fmax(bv, __shfl_xor(bv, 2));
    bv = fmax(bv, __shfl_xor(bv, 4));
    bv = fmax(bv, __shfl_xor(bv, 8));
    if (lv[KNN - 1] == bv) {  // exactly one lane per row owns the winner
#pragma unroll
      for (int s = KNN - 1; s > 0; --s) lv[s] = lv[s - 1];
      lv[0] = -1.0;
    }
    if (ssub == 0)
      op[round] =
          2047 - (int)((unsigned long long)(__double_as_longlong(bv) >> 19) & 0x7FFull);
  }
}

// ---------- per-point conv1 factoring ----------
template <int C>
__global__ __launch_bounds__(256) __attribute__((amdgpu_waves_per_eu(4, 4))) void
pointconv_kernel(const float* __restrict__ x, int bStride, const float* __restrict__ W,
                 float* __restrict__ znb, float* __restrict__ base) {
  const int blk = blockIdx.x;
  const int b = blk >> 5;
  const int nc = blk & 31;
  const int nl = threadIdx.x & 63;
  const int q = __builtin_amdgcn_readfirstlane(threadIdx.x >> 6);  // 0..3
  const int n = nc * 64 + nl;
  const float* xb = x + (size_t)b * bStride;

  float fz[16], fb[16];
#pragma unroll
  for (int t = 0; t < 16; ++t) { fz[t] = 0.f; fb[t] = 0.f; }
#pragma unroll 4
  for (int c = 0; c < C; ++c) {
    float xv = xb[(size_t)c * NPTS + n];
#pragma unroll
    for (int t = 0; t < 16; ++t) {
      float w0 = W[(q * 16 + t) * 2 * C + c];
      float w1 = W[(q * 16 + t) * 2 * C + C + c];
      fz[t] = fmaf(w0, xv, fz[t]);
      fb[t] = fmaf(w1 - w0, xv, fb[t]);
    }
  }
  const size_t o0 = ((size_t)(b * NPTS + n)) * 64 + q * 16;
#pragma unroll
  for (int t = 0; t < 16; t += 4)
    *(float4*)&znb[o0 + t] = make_float4(fz[t], fz[t + 1], fz[t + 2], fz[t + 3]);
#pragma unroll
  for (int t = 0; t < 16; t += 4)
    *(float4*)&base[o0 + t] = make_float4(fb[t], fb[t + 1], fb[t + 2], fb[t + 3]);
}

// ---------- fused edge kernel ----------
template <bool TWO>
__global__ __launch_bounds__(256) __attribute__((amdgpu_waves_per_eu(2, 4))) void edge_kernel(
    const float* __restrict__ znb, const float* __restrict__ base,
    const int* __restrict__ idx, const float* __restrict__ s1, const float* __restrict__ b1,
    const float* __restrict__ W2, const float* __restrict__ s2, const float* __restrict__ b2,
    float* __restrict__ xout) {
  __shared__ float baseS[12][64];
  const int tid = threadIdx.x;
  const int gp0 = blockIdx.x * 12;

  for (int t = tid; t < 12 * 64; t += 256) {
    int p = t >> 6, cp = t & 63;
    int gpt = gp0 + p;
    baseS[p][cp] = (gpt < NBATCH * NPTS) ? base[(size_t)gpt * 64 + cp] : 0.f;
  }
  __syncthreads();

  const int lane = tid & 63;
  const int wv = __builtin_amdgcn_readfirstlane(tid >> 6);
  int p = lane / 20;
  const int k = lane - p * 20;
  const bool pact = (p < 3);
  if (!pact) p = 2;
  const int pl = wv * 3 + p;
  const int gpt = gp0 + pl;
  const bool act = pact && (gpt < NBATCH * NPTS);
  const int gptc = (gpt < NBATCH * NPTS) ? gpt : (NBATCH * NPTS - 1);
  const int bb = gptc >> 11;
  const int nn = gptc & (NPTS - 1);
  const int m = idx[(size_t)gptc * KNN + k];
  const float* zg = znb + ((size_t)bb * NPTS + m) * 64;

  float y1[64];
#pragma unroll
  for (int c4 = 0; c4 < 64; c4 += 4) {
    float4 zv = *(const float4*)&zg[c4];
    float4 bv = *(const float4*)&baseS[pl][c4];
    y1[c4 + 0] = zv.x + bv.x;
    y1[c4 + 1] = zv.y + bv.y;
    y1[c4 + 2] = zv.z + bv.z;
    y1[c4 + 3] = zv.w + bv.w;
  }
#pragma unroll
  for (int cp = 0; cp < 64; ++cp) y1[cp] = lrelu(fmaf(y1[cp], s1[cp], b1[cp]));

  if constexpr (TWO) {
#pragma unroll 2
    for (int o2 = 0; o2 < 64; ++o2) {
      float a = 0.f;
#pragma unroll
      for (int c = 0; c < 64; ++c) a = fmaf(W2[o2 * 64 + c], y1[c], a);
      float z = lrelu(fmaf(a, s2[o2], b2[o2]));
#pragma unroll
      for (int off = 1; off < 32; off <<= 1) {
        float ov = __shfl_down(z, off);
        if (k + off < KNN) z = fmaxf(z, ov);
      }
      if (act && k == 0) xout[((size_t)bb * 64 + o2) * NPTS + nn] = z;
    }
  } else {
#pragma unroll 2
    for (int o2 = 0; o2 < 64; ++o2) {
      float z = y1[o2];
#pragma unroll
      for (int off = 1; off < 32; off <<= 1) {
        float ov = __shfl_down(z, off);
        if (k + off < KNN) z = fmaxf(z, ov);
      }
      if (act && k == 0) xout[((size_t)bb * 64 + o2) * NPTS + nn] = z;
    }
  }
}

// ---------- x4 = lrelu(s4*(W4·[x1;x2;x3])+b4), partial max ----------
__global__ __launch_bounds__(256) void x4max_kernel(const float* __restrict__ x1,
                                                    const float* __restrict__ x2,
                                                    const float* __restrict__ x3,
                                                    const float* __restrict__ W4,
                                                    const float* __restrict__ s4,
                                                    const float* __restrict__ b4,
                                                    float* __restrict__ pmax) {
  const int blk = blockIdx.x;
  const int b = blk >> 10;
  const int oc = (blk >> 5) & 31;
  const int nc = blk & 31;
  const int nl = threadIdx.x & 63;
  const int q = __builtin_amdgcn_readfirstlane(threadIdx.x >> 6);  // 0..3
  const int n = nc * 64 + nl;
  const float* xA = x1 + (size_t)b * 64 * NPTS;
  const float* xB = x2 + (size_t)b * 64 * NPTS;
  const float* xC = x3 + (size_t)b * 64 * NPTS;
  const float* wq = W4 + (size_t)(oc * 32 + q * 8) * 192;

  float f[8];
#pragma unroll
  for (int t = 0; t < 8; ++t) f[t] = 0.f;
#pragma unroll 2
  for (int cb = 0; cb < 64; cb += 4) {
    float xv0 = xA[(size_t)(cb + 0) * NPTS + n];
    float xv1 = xA[(size_t)(cb + 1) * NPTS + n];
    float xv2 = xA[(size_t)(cb + 2) * NPTS + n];
    float xv3 = xA[(size_t)(cb + 3) * NPTS + n];
#pragma unroll
    for (int t = 0; t < 8; ++t) {
      float4 wv = *(const float4*)&wq[(size_t)t * 192 + cb];
      f[t] = fmaf(wv.x, xv0, f[t]);
      f[t] = fmaf(wv.y, xv1, f[t]);
      f[t] = fmaf(wv.z, xv2, f[t]);
      f[t] = fmaf(wv.w, xv3, f[t]);
    }
  }
#pragma unroll 2
  for (int cb = 0; cb < 64; cb += 4) {
    float xv0 = xB[(size_t)(cb + 0) * NPTS + n];
    float xv1 = xB[(size_t)(cb + 1) * NPTS + n];
    float xv2 = xB[(size_t)(cb + 2) * NPTS + n];
    float xv3 = xB[(size_t)(cb + 3) * NPTS + n];
#pragma unroll
    for (int t = 0; t < 8; ++t) {
      float4 wv = *(const float4*)&wq[(size_t)t * 192 + 64 + cb];
      f[t] = fmaf(wv.x, xv0, f[t]);
      f[t] = fmaf(wv.y, xv1, f[t]);
      f[t] = fmaf(wv.z, xv2, f[t]);
      f[t] = fmaf(wv.w, xv3, f[t]);
    }
  }
#pragma unroll 2
  for (int cb = 0; cb < 64; cb += 4) {
    float xv0 = xC[(size_t)(cb + 0) * NPTS + n];
    float xv1 = xC[(size_t)(cb + 1) * NPTS + n];
    float xv2 = xC[(size_t)(cb + 2) * NPTS + n];
    float xv3 = xC[(size_t)(cb + 3) * NPTS + n];
#pragma unroll
    for (int t = 0; t < 8; ++t) {
      float4 wv = *(const float4*)&wq[(size_t)t * 192 + 128 + cb];
      f[t] = fmaf(wv.x, xv0, f[t]);
      f[t] = fmaf(wv.y, xv1, f[t]);
      f[t] = fmaf(wv.z, xv2, f[t]);
      f[t] = fmaf(wv.w, xv3, f[t]);
    }
  }
#pragma unroll
  for (int t = 0; t < 8; ++t) {
    const int o = oc * 32 + q * 8 + t;
    float v = lrelu(fmaf(f[t], s4[o], b4[o]));
#pragma unroll
    for (int off = 32; off; off >>= 1) v = fmaxf(v, __shfl_down(v, off));
    if (nl == 0) pmax[(size_t)(b * 1024 + o) * 32 + nc] = v;
  }
}

__global__ __launch_bounds__(256) void gmax_kernel(const float* __restrict__ pmax,
                                                   float* __restrict__ g) {
  int i = blockIdx.x * 256 + threadIdx.x;
  if (i >= NBATCH * 1024) return;
  float v = -__builtin_inff();
#pragma unroll
  for (int j = 0; j < 32; ++j) v = fmaxf(v, pmax[(size_t)i * 32 + j]);
  g[i] = v;
}

__global__ __launch_bounds__(256) void t5a_kernel(const float* __restrict__ g,
                                                  const float* __restrict__ w5a,
                                                  float* __restrict__ t5a) {
  const int task = blockIdx.x * 4 + (threadIdx.x >> 6);  // 0..4095
  const int lane = threadIdx.x & 63;
  const int b = task >> 9;
  const int o5 = task & 511;
  float acc = 0.f;
  for (int c = lane; c < 1024; c += 64) acc = fmaf(w5a[(size_t)o5 * 1216 + c], g[b * 1024 + c], acc);
#pragma unroll
  for (int off = 32; off; off >>= 1) acc += __shfl_down(acc, off);
  if (lane == 0) t5a[task] = acc;
}

// ---------- head: a(512) -> h2(256) -> out(13), per 64-column tile ----------
// LDS (80KB) caps occupancy at 1 block/CU = 4 waves/EU; waves_per_eu(4,4)
// aligns the register budget (128). Deeper unrolls (8 / 4) widen the
// scalar-load hoisting window to cover SMEM latency at fixed occupancy.
__global__ __launch_bounds__(1024) __attribute__((amdgpu_waves_per_eu(4, 4))) void head_kernel(
    const float* __restrict__ x1, const float* __restrict__ x2, const float* __restrict__ x3,
    const float* __restrict__ t5a, const float* __restrict__ w5a, const float* __restrict__ s5a,
    const float* __restrict__ b5a, const float* __restrict__ w5b, const float* __restrict__ s5b,
    const float* __restrict__ b5b, const float* __restrict__ w6, float* __restrict__ out) {
  __shared__ float xls[192 * 64];
  __shared__ float als[2][64 * 64];
  const int tid = threadIdx.x;
  const int nl = tid & 63;
  const int q = __builtin_amdgcn_readfirstlane(tid >> 6);  // 0..15
  const int blk = blockIdx.x;
  const int b = blk >> 5;
  const int n0 = (blk & 31) * 64;

  for (int t = tid; t < 192 * 64; t += 1024) {
    int c = t >> 6, j = t & 63;
    const float* xp = (c < 64) ? x1 : ((c < 128) ? x2 : x3);
    xls[t] = xp[((size_t)b * 64 + (c & 63)) * NPTS + n0 + j];
  }
  __syncthreads();

  float h2[16];
#pragma unroll
  for (int t = 0; t < 16; ++t) h2[t] = 0.f;

#pragma unroll 1
  for (int ch = 0; ch < 8; ++ch) {
    float a[4];
#pragma unroll
    for (int t = 0; t < 4; ++t) a[t] = t5a[b * 512 + ch * 64 + q + 16 * t];
#pragma unroll 8
    for (int cb = 0; cb < 192; cb += 4) {
      float xv0 = xls[(cb + 0) * 64 + nl];
      float xv1 = xls[(cb + 1) * 64 + nl];
      float xv2 = xls[(cb + 2) * 64 + nl];
      float xv3 = xls[(cb + 3) * 64 + nl];
#pragma unroll
      for (int t = 0; t < 4; ++t) {
        float4 wv = *(const float4*)&w5a[(size_t)(ch * 64 + q + 16 * t) * 1216 + 1024 + cb];
        a[t] = fmaf(wv.x, xv0, a[t]);
        a[t] = fmaf(wv.y, xv1, a[t]);
        a[t] = fmaf(wv.z, xv2, a[t]);
        a[t] = fmaf(wv.w, xv3, a[t]);
      }
    }
    float* alsb = als[ch & 1];
#pragma unroll
    for (int t = 0; t < 4; ++t) {
      const int oa = ch * 64 + q + 16 * t;
      alsb[(q + 16 * t) * 64 + nl] = lrelu(fmaf(a[t], s5a[oa], b5a[oa]));
    }
    __syncthreads();  // alsb fully written; prior-parity reads done 1 chunk ago
#pragma unroll 4
    for (int ca = 0; ca < 64; ca += 4) {
      float av0 = alsb[(ca + 0) * 64 + nl];
      float av1 = alsb[(ca + 1) * 64 + nl];
      float av2 = alsb[(ca + 2) * 64 + nl];
      float av3 = alsb[(ca + 3) * 64 + nl];
#pragma unroll
      for (int t = 0; t < 16; ++t) {
        float4 wv = *(const float4*)&w5b[(size_t)(q + 16 * t) * 512 + ch * 64 + ca];
        h2[t] = fmaf(wv.x, av0, h2[t]);
        h2[t] = fmaf(wv.y, av1, h2[t]);
        h2[t] = fmaf(wv.z, av2, h2[t]);
        h2[t] = fmaf(wv.w, av3, h2[t]);
      }
    }
  }
#pragma unroll
  for (int t = 0; t < 16; ++t) {
    const int o2 = q + 16 * t;
    h2[t] = lrelu(fmaf(h2[t], s5b[o2], b5b[o2]));
  }
  float pq[13];
#pragma unroll
  for (int o = 0; o < 13; ++o) {
    float s = 0.f;
#pragma unroll
    for (int t = 0; t < 16; ++t) s = fmaf(w6[o * 256 + q + 16 * t], h2[t], s);
    pq[o] = s;
  }
  // reduce 16 wave-partials -> 8 (waves 8..15 add into 0..7's slots), then tree
  __syncthreads();  // xls reads all done; safe to overwrite
  if (q < 8) {
#pragma unroll
    for (int o = 0; o < 13; ++o) xls[(q * 13 + o) * 64 + nl] = pq[o];
  }
  __syncthreads();
  if (q >= 8) {
#pragma unroll
    for (int o = 0; o < 13; ++o) xls[((q - 8) * 13 + o) * 64 + nl] += pq[o];
  }
  __syncthreads();
  for (int t = tid; t < 13 * 64; t += 1024) {
    int o = t >> 6, j = t & 63;
    float s = 0.f;
#pragma unroll
    for (int qq = 0; qq < 8; ++qq) s += xls[(qq * 13 + o) * 64 + j];
    out[((size_t)b * 13 + o) * NPTS + n0 + j] = s;
  }
}

}  // namespace

extern "C" void kernel_launch(void* const* d_in, const int* in_sizes, int n_in, void* d_out,
                              int out_size, void* d_ws, size_t ws_size, hipStream_t stream) {
  (void)in_sizes; (void)n_in; (void)out_size;
  const float* x = (const float*)d_in[0];
  const float* w1a = (const float*)d_in[1];
  const float* s1a = (const float*)d_in[2];
  const float* b1a = (const float*)d_in[3];
  const float* w1b = (const float*)d_in[4];
  const float* s1b = (const float*)d_in[5];
  const float* b1b = (const float*)d_in[6];
  const float* w2a = (const float*)d_in[7];
  const float* s2a = (const float*)d_in[8];
  const float* b2a = (const float*)d_in[9];
  const float* w2b = (const float*)d_in[10];
  const float* s2b = (const float*)d_in[11];
  const float* b2b = (const float*)d_in[12];
  const float* w3 = (const float*)d_in[13];
  const float* s3 = (const float*)d_in[14];
  const float* b3 = (const float*)d_in[15];
  const float* w4 = (const float*)d_in[16];
  const float* s4 = (const float*)d_in[17];
  const float* b4 = (const float*)d_in[18];
  const float* w5a = (const float*)d_in[19];
  const float* s5a = (const float*)d_in[20];
  const float* b5a = (const float*)d_in[21];
  const float* w5b = (const float*)d_in[22];
  const float* s5b = (const float*)d_in[23];
  const float* b5b = (const float*)d_in[24];
  const float* w6 = (const float*)d_in[25];
  float* out = (float*)d_out;

  char* wsp = (char*)d_ws;
  size_t off = 0;
  auto alloc = [&](size_t bytes) -> void* {
    void* p = wsp + off;
    off += (bytes + 255) & ~(size_t)255;
    return p;
  };
  int* idx1 = (int*)alloc((size_t)NBATCH * NPTS * KNN * 4);
  int* idx2 = (int*)alloc((size_t)NBATCH * NPTS * KNN * 4);
  int* idx3 = (int*)alloc((size_t)NBATCH * NPTS * KNN * 4);
  float* x1 = (float*)alloc((size_t)NBATCH * 64 * NPTS * 4);
  float* x2 = (float*)alloc((size_t)NBATCH * 64 * NPTS * 4);
  float* x3 = (float*)alloc((size_t)NBATCH * 64 * NPTS * 4);
  float* znbBuf = (float*)alloc((size_t)NBATCH * NPTS * 64 * 4);
  float* baseBuf = (float*)alloc((size_t)NBATCH * NPTS * 64 * 4);
  float* pmaxb = (float*)alloc((size_t)NBATCH * 1024 * 32 * 4);
  float* g = (float*)alloc((size_t)NBATCH * 1024 * 4);
  float* t5a = (float*)alloc((size_t)NBATCH * 512 * 4);

  // Workspace overflow would corrupt device memory (hang risk). Fail fast.
  if (off > ws_size) return;

  const int knnGrid = NBATCH * NPTS / 32;             // 512
  const int ecGrid = (NBATCH * NPTS + 11) / 12;       // 1366
  const int pcGrid = NBATCH * 32;                     // 256

  knn_kernel<3><<<knnGrid, 512, 0, stream>>>(x + 6 * NPTS, NPTS, 9 * NPTS, idx1);
  pointconv_kernel<9><<<pcGrid, 256, 0, stream>>>(x, 9 * NPTS, w1a, znbBuf, baseBuf);
  edge_kernel<true><<<ecGrid, 256, 0, stream>>>(znbBuf, baseBuf, idx1, s1a, b1a, w1b, s1b, b1b,
                                                x1);
  knn_kernel<64><<<knnGrid, 512, 0, stream>>>(x1, NPTS, 64 * NPTS, idx2);
  pointconv_kernel<64><<<pcGrid, 256, 0, stream>>>(x1, 64 * NPTS, w2a, znbBuf, baseBuf);
  edge_kernel<true><<<ecGrid, 256, 0, stream>>>(znbBuf, baseBuf, idx2, s2a, b2a, w2b, s2b, b2b,
                                                x2);
  knn_kernel<64><<<knnGrid, 512, 0, stream>>>(x2, NPTS, 64 * NPTS, idx3);
  pointconv_kernel<64><<<pcGrid, 256, 0, stream>>>(x2, 64 * NPTS, w3, znbBuf, baseBuf);
  edge_kernel<false><<<ecGrid, 256, 0, stream>>>(znbBuf, baseBuf, idx3, s3, b3, nullptr, nullptr,
                                                 nullptr, x3);
  x4max_kernel<<<8192, 256, 0, stream>>>(x1, x2, x3, w4, s4, b4, pmaxb);
  gmax_kernel<<<32, 256, 0, stream>>>(pmaxb, g);
  t5a_kernel<<<1024, 256, 0, stream>>>(g, w5a, t5a);
  head_kernel<<<256, 1024, 0, stream>>>(x1, x2, x3, t5a, w5a, s5a, b5a, w5b, s5b, b5b, w6, out);
}

// Round 21
// 1040.146 us; speedup vs baseline: 1.0270x; 1.0270x over previous
//
#include <hip/hip_runtime.h>
#include <cstddef>
#include <cstdint>

namespace {

constexpr int NBATCH = 8;
constexpr int NPTS = 2048;
constexpr int KNN = 20;

__device__ __forceinline__ float lrelu(float v) { return fmaxf(v, 0.2f * v); }

// ---------- KNN: top-20 neighbors by neg squared distance ----------
// Keys packed into positive doubles: bits = sortable32(dist)<<30 |
// (2047-idx)<<19 -> double order == (exact f32 dist, then smaller index);
// keys unique -> lax.top_k set semantics. Branch-free per-lane sorted top-20
// via the carry-free min/max identity (39 f64 ops, 2-op critical path).
// 512 threads: 8 waves x 4 rows (dot), 16 lanes/row x 128 cand (select).
template <int C>
__global__ __launch_bounds__(512) void knn_kernel(const float* __restrict__ x, int chStride,
                                                  int bStride, int* __restrict__ idxOut) {
  constexpr int CP = (C + 3) & ~3;   // padded channels
  constexpr int MT = 128;            // columns per tile
  constexpr int ROWS = 32;           // rows per block
  constexpr int RPW = 4;             // rows per wave (dot phase)
  constexpr int LPR = 16;            // lanes per row (select phase)
  constexpr int DS = MT + 4;         // dist row stride (132 -> 2-way, free)
  constexpr int NT = NPTS / MT;      // 16 tiles

  __shared__ float qt[ROWS * CP];
  __shared__ float xt[CP * MT];      // column-major: xt[c*MT + m]
  __shared__ float dist[ROWS * DS];

  const int tid = threadIdx.x;
  const int lane = tid & 63;
  const int wv = tid >> 6;           // 0..7
  const int r0 = wv * RPW;
  const int b = blockIdx.x / (NPTS / ROWS);
  const int n0 = (blockIdx.x % (NPTS / ROWS)) * ROWS;
  const float* xb = x + (size_t)b * bStride;

  for (int t = tid; t < ROWS * CP; t += 512) {
    int r = t / CP, c = t % CP;
    qt[r * CP + c] = (c < C) ? xb[(size_t)c * chStride + n0 + r] : 0.f;
  }
  __syncthreads();

  // per-row query self-dot (broadcast LDS reads)
  float xn[RPW];
#pragma unroll
  for (int r = 0; r < RPW; ++r) {
    float s = 0.f;
#pragma unroll
    for (int cb = 0; cb < CP; cb += 4) {
      float4 qv = *(const float4*)&qt[(r0 + r) * CP + cb];
      s = fmaf(qv.x, qv.x, s);
      s = fmaf(qv.y, qv.y, s);
      s = fmaf(qv.z, qv.z, s);
      s = fmaf(qv.w, qv.w, s);
    }
    xn[r] = s;
  }

  // selection state: 16 lanes/row, per-lane sorted-ascending top-20 keys
  const int srow = tid >> 4;         // 0..31
  const int ssub = tid & 15;
  double lv[KNN];
#pragma unroll
  for (int s = 0; s < KNN; ++s) lv[s] = -1.0;  // below all packed keys (>=0)

  // running index-key part: (2047 - gidx) << 19, gidx = mt*128 + j*16 + ssub
  unsigned long long ib = (unsigned long long)(2047 - ssub) << 19;

#pragma unroll 1
  for (int mt = 0; mt < NT; ++mt) {
    __syncthreads();  // all waves done reading xt of previous tile
    {
      const float4 z4 = make_float4(0.f, 0.f, 0.f, 0.f);
      for (int t = tid; t < CP * MT / 4; t += 512) {
        int f = t * 4;
        int c = f >> 7, m = f & (MT - 1);
        *(float4*)&xt[f] =
            (c < C) ? *(const float4*)&xb[(size_t)c * chStride + mt * MT + m] : z4;
      }
    }
    __syncthreads();  // xt ready

    float acc0[RPW], acc1[RPW];
    float xm0 = 0.f, xm1 = 0.f;
#pragma unroll
    for (int r = 0; r < RPW; ++r) { acc0[r] = 0.f; acc1[r] = 0.f; }
#pragma unroll 1
    for (int cb = 0; cb < CP; cb += 4) {
      float x00 = xt[(cb + 0) * MT + lane];
      float x01 = xt[(cb + 1) * MT + lane];
      float x02 = xt[(cb + 2) * MT + lane];
      float x03 = xt[(cb + 3) * MT + lane];
      float x10 = xt[(cb + 0) * MT + 64 + lane];
      float x11 = xt[(cb + 1) * MT + 64 + lane];
      float x12 = xt[(cb + 2) * MT + 64 + lane];
      float x13 = xt[(cb + 3) * MT + 64 + lane];
      xm0 = fmaf(x00, x00, xm0);
      xm0 = fmaf(x01, x01, xm0);
      xm0 = fmaf(x02, x02, xm0);
      xm0 = fmaf(x03, x03, xm0);
      xm1 = fmaf(x10, x10, xm1);
      xm1 = fmaf(x11, x11, xm1);
      xm1 = fmaf(x12, x12, xm1);
      xm1 = fmaf(x13, x13, xm1);
#pragma unroll
      for (int r = 0; r < RPW; ++r) {
        float4 qv = *(const float4*)&qt[(r0 + r) * CP + cb];
        acc0[r] = fmaf(qv.x, x00, acc0[r]);
        acc0[r] = fmaf(qv.y, x01, acc0[r]);
        acc0[r] = fmaf(qv.z, x02, acc0[r]);
        acc0[r] = fmaf(qv.w, x03, acc0[r]);
        acc1[r] = fmaf(qv.x, x10, acc1[r]);
        acc1[r] = fmaf(qv.y, x11, acc1[r]);
        acc1[r] = fmaf(qv.z, x12, acc1[r]);
        acc1[r] = fmaf(qv.w, x13, acc1[r]);
      }
    }
#pragma unroll
    for (int r = 0; r < RPW; ++r) {
      dist[(r0 + r) * DS + lane] = 2.f * acc0[r] - xn[r] - xm0;
      dist[(r0 + r) * DS + 64 + lane] = 2.f * acc1[r] - xn[r] - xm1;
    }
    // rows r0..r0+3 are read below by lanes of this same wave -> no barrier

    // per-lane: pack candidate into key, branch-free sorted insert
#pragma unroll
    for (int j = 0; j < MT / LPR; ++j) {
      float val = dist[srow * DS + j * LPR + ssub];
      unsigned int u = __float_as_uint(val);
      u ^= (unsigned int)(((int)u) >> 31) | 0x80000000u;
      double kd = __longlong_as_double((long long)(((unsigned long long)u << 30) | ib));
      ib -= (unsigned long long)LPR << 19;
#pragma unroll
      for (int s = 0; s < KNN - 1; ++s) lv[s] = fmin(lv[s + 1], fmax(lv[s], kd));
      lv[KNN - 1] = fmax(lv[KNN - 1], kd);
    }
  }

  // merge 16 lanes' lists per row: keys unique -> single-owner pop per round
  int* op = idxOut + ((size_t)b * NPTS + n0 + srow) * KNN;
#pragma unroll 1
  for (int round = 0; round < KNN; ++round) {
    double bv = lv[KNN - 1];
    bv = fmax(bv, __shfl_xor(bv, 1));
    bv = fmax(bv, __shfl_xor(bv, 2));
    bv = fmax(bv, __shfl_xor(bv, 4));
    bv = fmax(bv, __shfl_xor(bv, 8));
    if (lv[KNN - 1] == bv) {  // exactly one lane per row owns the winner
#pragma unroll
      for (int s = KNN - 1; s > 0; --s) lv[s] = lv[s - 1];
      lv[0] = -1.0;
    }
    if (ssub == 0)
      op[round] =
          2047 - (int)((unsigned long long)(__double_as_longlong(bv) >> 19) & 0x7FFull);
  }
}

// ---------- per-point conv1 factoring ----------
template <int C>
__global__ __launch_bounds__(256) __attribute__((amdgpu_waves_per_eu(4, 4))) void
pointconv_kernel(const float* __restrict__ x, int bStride, const float* __restrict__ W,
                 float* __restrict__ znb, float* __restrict__ base) {
  const int blk = blockIdx.x;
  const int b = blk >> 5;
  const int nc = blk & 31;
  const int nl = threadIdx.x & 63;
  const int q = __builtin_amdgcn_readfirstlane(threadIdx.x >> 6);  // 0..3
  const int n = nc * 64 + nl;
  const float* xb = x + (size_t)b * bStride;

  float fz[16], fb[16];
#pragma unroll
  for (int t = 0; t < 16; ++t) { fz[t] = 0.f; fb[t] = 0.f; }
#pragma unroll 4
  for (int c = 0; c < C; ++c) {
    float xv = xb[(size_t)c * NPTS + n];
#pragma unroll
    for (int t = 0; t < 16; ++t) {
      float w0 = W[(q * 16 + t) * 2 * C + c];
      float w1 = W[(q * 16 + t) * 2 * C + C + c];
      fz[t] = fmaf(w0, xv, fz[t]);
      fb[t] = fmaf(w1 - w0, xv, fb[t]);
    }
  }
  const size_t o0 = ((size_t)(b * NPTS + n)) * 64 + q * 16;
#pragma unroll
  for (int t = 0; t < 16; t += 4)
    *(float4*)&znb[o0 + t] = make_float4(fz[t], fz[t + 1], fz[t + 2], fz[t + 3]);
#pragma unroll
  for (int t = 0; t < 16; t += 4)
    *(float4*)&base[o0 + t] = make_float4(fb[t], fb[t + 1], fb[t + 2], fb[t + 3]);
}

// ---------- fused edge kernel ----------
template <bool TWO>
__global__ __launch_bounds__(256) __attribute__((amdgpu_waves_per_eu(2, 4))) void edge_kernel(
    const float* __restrict__ znb, const float* __restrict__ base,
    const int* __restrict__ idx, const float* __restrict__ s1, const float* __restrict__ b1,
    const float* __restrict__ W2, const float* __restrict__ s2, const float* __restrict__ b2,
    float* __restrict__ xout) {
  __shared__ float baseS[12][64];
  const int tid = threadIdx.x;
  const int gp0 = blockIdx.x * 12;

  for (int t = tid; t < 12 * 64; t += 256) {
    int p = t >> 6, cp = t & 63;
    int gpt = gp0 + p;
    baseS[p][cp] = (gpt < NBATCH * NPTS) ? base[(size_t)gpt * 64 + cp] : 0.f;
  }
  __syncthreads();

  const int lane = tid & 63;
  const int wv = __builtin_amdgcn_readfirstlane(tid >> 6);
  int p = lane / 20;
  const int k = lane - p * 20;
  const bool pact = (p < 3);
  if (!pact) p = 2;
  const int pl = wv * 3 + p;
  const int gpt = gp0 + pl;
  const bool act = pact && (gpt < NBATCH * NPTS);
  const int gptc = (gpt < NBATCH * NPTS) ? gpt : (NBATCH * NPTS - 1);
  const int bb = gptc >> 11;
  const int nn = gptc & (NPTS - 1);
  const int m = idx[(size_t)gptc * KNN + k];
  const float* zg = znb + ((size_t)bb * NPTS + m) * 64;

  float y1[64];
#pragma unroll
  for (int c4 = 0; c4 < 64; c4 += 4) {
    float4 zv = *(const float4*)&zg[c4];
    float4 bv = *(const float4*)&baseS[pl][c4];
    y1[c4 + 0] = zv.x + bv.x;
    y1[c4 + 1] = zv.y + bv.y;
    y1[c4 + 2] = zv.z + bv.z;
    y1[c4 + 3] = zv.w + bv.w;
  }
#pragma unroll
  for (int cp = 0; cp < 64; ++cp) y1[cp] = lrelu(fmaf(y1[cp], s1[cp], b1[cp]));

  if constexpr (TWO) {
#pragma unroll 2
    for (int o2 = 0; o2 < 64; ++o2) {
      float a = 0.f;
#pragma unroll
      for (int c = 0; c < 64; ++c) a = fmaf(W2[o2 * 64 + c], y1[c], a);
      float z = lrelu(fmaf(a, s2[o2], b2[o2]));
#pragma unroll
      for (int off = 1; off < 32; off <<= 1) {
        float ov = __shfl_down(z, off);
        if (k + off < KNN) z = fmaxf(z, ov);
      }
      if (act && k == 0) xout[((size_t)bb * 64 + o2) * NPTS + nn] = z;
    }
  } else {
#pragma unroll 2
    for (int o2 = 0; o2 < 64; ++o2) {
      float z = y1[o2];
#pragma unroll
      for (int off = 1; off < 32; off <<= 1) {
        float ov = __shfl_down(z, off);
        if (k + off < KNN) z = fmaxf(z, ov);
      }
      if (act && k == 0) xout[((size_t)bb * 64 + o2) * NPTS + nn] = z;
    }
  }
}

// ---------- x4 = lrelu(s4*(W4·[x1;x2;x3])+b4), partial max ----------
__global__ __launch_bounds__(256) void x4max_kernel(const float* __restrict__ x1,
                                                    const float* __restrict__ x2,
                                                    const float* __restrict__ x3,
                                                    const float* __restrict__ W4,
                                                    const float* __restrict__ s4,
                                                    const float* __restrict__ b4,
                                                    float* __restrict__ pmax) {
  const int blk = blockIdx.x;
  const int b = blk >> 10;
  const int oc = (blk >> 5) & 31;
  const int nc = blk & 31;
  const int nl = threadIdx.x & 63;
  const int q = __builtin_amdgcn_readfirstlane(threadIdx.x >> 6);  // 0..3
  const int n = nc * 64 + nl;
  const float* xA = x1 + (size_t)b * 64 * NPTS;
  const float* xB = x2 + (size_t)b * 64 * NPTS;
  const float* xC = x3 + (size_t)b * 64 * NPTS;
  const float* wq = W4 + (size_t)(oc * 32 + q * 8) * 192;

  float f[8];
#pragma unroll
  for (int t = 0; t < 8; ++t) f[t] = 0.f;
#pragma unroll 2
  for (int cb = 0; cb < 64; cb += 4) {
    float xv0 = xA[(size_t)(cb + 0) * NPTS + n];
    float xv1 = xA[(size_t)(cb + 1) * NPTS + n];
    float xv2 = xA[(size_t)(cb + 2) * NPTS + n];
    float xv3 = xA[(size_t)(cb + 3) * NPTS + n];
#pragma unroll
    for (int t = 0; t < 8; ++t) {
      float4 wv = *(const float4*)&wq[(size_t)t * 192 + cb];
      f[t] = fmaf(wv.x, xv0, f[t]);
      f[t] = fmaf(wv.y, xv1, f[t]);
      f[t] = fmaf(wv.z, xv2, f[t]);
      f[t] = fmaf(wv.w, xv3, f[t]);
    }
  }
#pragma unroll 2
  for (int cb = 0; cb < 64; cb += 4) {
    float xv0 = xB[(size_t)(cb + 0) * NPTS + n];
    float xv1 = xB[(size_t)(cb + 1) * NPTS + n];
    float xv2 = xB[(size_t)(cb + 2) * NPTS + n];
    float xv3 = xB[(size_t)(cb + 3) * NPTS + n];
#pragma unroll
    for (int t = 0; t < 8; ++t) {
      float4 wv = *(const float4*)&wq[(size_t)t * 192 + 64 + cb];
      f[t] = fmaf(wv.x, xv0, f[t]);
      f[t] = fmaf(wv.y, xv1, f[t]);
      f[t] = fmaf(wv.z, xv2, f[t]);
      f[t] = fmaf(wv.w, xv3, f[t]);
    }
  }
#pragma unroll 2
  for (int cb = 0; cb < 64; cb += 4) {
    float xv0 = xC[(size_t)(cb + 0) * NPTS + n];
    float xv1 = xC[(size_t)(cb + 1) * NPTS + n];
    float xv2 = xC[(size_t)(cb + 2) * NPTS + n];
    float xv3 = xC[(size_t)(cb + 3) * NPTS + n];
#pragma unroll
    for (int t = 0; t < 8; ++t) {
      float4 wv = *(const float4*)&wq[(size_t)t * 192 + 128 + cb];
      f[t] = fmaf(wv.x, xv0, f[t]);
      f[t] = fmaf(wv.y, xv1, f[t]);
      f[t] = fmaf(wv.z, xv2, f[t]);
      f[t] = fmaf(wv.w, xv3, f[t]);
    }
  }
#pragma unroll
  for (int t = 0; t < 8; ++t) {
    const int o = oc * 32 + q * 8 + t;
    float v = lrelu(fmaf(f[t], s4[o], b4[o]));
#pragma unroll
    for (int off = 32; off; off >>= 1) v = fmaxf(v, __shfl_down(v, off));
    if (nl == 0) pmax[(size_t)(b * 1024 + o) * 32 + nc] = v;
  }
}

__global__ __launch_bounds__(256) void gmax_kernel(const float* __restrict__ pmax,
                                                   float* __restrict__ g) {
  int i = blockIdx.x * 256 + threadIdx.x;
  if (i >= NBATCH * 1024) return;
  float v = -__builtin_inff();
#pragma unroll
  for (int j = 0; j < 32; ++j) v = fmaxf(v, pmax[(size_t)i * 32 + j]);
  g[i] = v;
}

__global__ __launch_bounds__(256) void t5a_kernel(const float* __restrict__ g,
                                                  const float* __restrict__ w5a,
                                                  float* __restrict__ t5a) {
  const int task = blockIdx.x * 4 + (threadIdx.x >> 6);  // 0..4095
  const int lane = threadIdx.x & 63;
  const int b = task >> 9;
  const int o5 = task & 511;
  float acc = 0.f;
  for (int c = lane; c < 1024; c += 64) acc = fmaf(w5a[(size_t)o5 * 1216 + c], g[b * 1024 + c], acc);
#pragma unroll
  for (int off = 32; off; off >>= 1) acc += __shfl_down(acc, off);
  if (lane == 0) t5a[task] = acc;
}

// ---------- head: a(512) -> h2(256) -> out(13), per 64-column tile ----------
// Single-buffered als: LDS 64KB (48K xls + 16K als) -> 2 blocks/CU = 32
// waves/CU (vs 80KB double-buffer = 1 block = 16 waves). VGPR need measured
// at 52 <= 64, so waves_per_eu(8,8) occupancy is register-feasible. Extra
// barrier per chunk is covered by the co-resident block's waves.
__global__ __launch_bounds__(1024) __attribute__((amdgpu_waves_per_eu(8, 8))) void head_kernel(
    const float* __restrict__ x1, const float* __restrict__ x2, const float* __restrict__ x3,
    const float* __restrict__ t5a, const float* __restrict__ w5a, const float* __restrict__ s5a,
    const float* __restrict__ b5a, const float* __restrict__ w5b, const float* __restrict__ s5b,
    const float* __restrict__ b5b, const float* __restrict__ w6, float* __restrict__ out) {
  __shared__ float xls[192 * 64];
  __shared__ float als[64 * 64];
  const int tid = threadIdx.x;
  const int nl = tid & 63;
  const int q = __builtin_amdgcn_readfirstlane(tid >> 6);  // 0..15
  const int blk = blockIdx.x;
  const int b = blk >> 5;
  const int n0 = (blk & 31) * 64;

  for (int t = tid; t < 192 * 64; t += 1024) {
    int c = t >> 6, j = t & 63;
    const float* xp = (c < 64) ? x1 : ((c < 128) ? x2 : x3);
    xls[t] = xp[((size_t)b * 64 + (c & 63)) * NPTS + n0 + j];
  }
  __syncthreads();

  float h2[16];
#pragma unroll
  for (int t = 0; t < 16; ++t) h2[t] = 0.f;

#pragma unroll 1
  for (int ch = 0; ch < 8; ++ch) {
    float a[4];
#pragma unroll
    for (int t = 0; t < 4; ++t) a[t] = t5a[b * 512 + ch * 64 + q + 16 * t];
#pragma unroll 4
    for (int cb = 0; cb < 192; cb += 4) {
      float xv0 = xls[(cb + 0) * 64 + nl];
      float xv1 = xls[(cb + 1) * 64 + nl];
      float xv2 = xls[(cb + 2) * 64 + nl];
      float xv3 = xls[(cb + 3) * 64 + nl];
#pragma unroll
      for (int t = 0; t < 4; ++t) {
        float4 wv = *(const float4*)&w5a[(size_t)(ch * 64 + q + 16 * t) * 1216 + 1024 + cb];
        a[t] = fmaf(wv.x, xv0, a[t]);
        a[t] = fmaf(wv.y, xv1, a[t]);
        a[t] = fmaf(wv.z, xv2, a[t]);
        a[t] = fmaf(wv.w, xv3, a[t]);
      }
    }
    __syncthreads();  // previous chunk's als reads all complete
#pragma unroll
    for (int t = 0; t < 4; ++t) {
      const int oa = ch * 64 + q + 16 * t;
      als[(q + 16 * t) * 64 + nl] = lrelu(fmaf(a[t], s5a[oa], b5a[oa]));
    }
    __syncthreads();  // als fully written
#pragma unroll 2
    for (int ca = 0; ca < 64; ca += 4) {
      float av0 = als[(ca + 0) * 64 + nl];
      float av1 = als[(ca + 1) * 64 + nl];
      float av2 = als[(ca + 2) * 64 + nl];
      float av3 = als[(ca + 3) * 64 + nl];
#pragma unroll
      for (int t = 0; t < 16; ++t) {
        float4 wv = *(const float4*)&w5b[(size_t)(q + 16 * t) * 512 + ch * 64 + ca];
        h2[t] = fmaf(wv.x, av0, h2[t]);
        h2[t] = fmaf(wv.y, av1, h2[t]);
        h2[t] = fmaf(wv.z, av2, h2[t]);
        h2[t] = fmaf(wv.w, av3, h2[t]);
      }
    }
  }
#pragma unroll
  for (int t = 0; t < 16; ++t) {
    const int o2 = q + 16 * t;
    h2[t] = lrelu(fmaf(h2[t], s5b[o2], b5b[o2]));
  }
  float pq[13];
#pragma unroll
  for (int o = 0; o < 13; ++o) {
    float s = 0.f;
#pragma unroll
    for (int t = 0; t < 16; ++t) s = fmaf(w6[o * 256 + q + 16 * t], h2[t], s);
    pq[o] = s;
  }
  // reduce 16 wave-partials -> 8 (waves 8..15 add into 0..7's slots), then tree
  __syncthreads();  // xls reads all done; safe to overwrite
  if (q < 8) {
#pragma unroll
    for (int o = 0; o < 13; ++o) xls[(q * 13 + o) * 64 + nl] = pq[o];
  }
  __syncthreads();
  if (q >= 8) {
#pragma unroll
    for (int o = 0; o < 13; ++o) xls[((q - 8) * 13 + o) * 64 + nl] += pq[o];
  }
  __syncthreads();
  for (int t = tid; t < 13 * 64; t += 1024) {
    int o = t >> 6, j = t & 63;
    float s = 0.f;
#pragma unroll
    for (int qq = 0; qq < 8; ++qq) s += xls[(qq * 13 + o) * 64 + j];
    out[((size_t)b * 13 + o) * NPTS + n0 + j] = s;
  }
}

}  // namespace

extern "C" void kernel_launch(void* const* d_in, const int* in_sizes, int n_in, void* d_out,
                              int out_size, void* d_ws, size_t ws_size, hipStream_t stream) {
  (void)in_sizes; (void)n_in; (void)out_size;
  const float* x = (const float*)d_in[0];
  const float* w1a = (const float*)d_in[1];
  const float* s1a = (const float*)d_in[2];
  const float* b1a = (const float*)d_in[3];
  const float* w1b = (const float*)d_in[4];
  const float* s1b = (const float*)d_in[5];
  const float* b1b = (const float*)d_in[6];
  const float* w2a = (const float*)d_in[7];
  const float* s2a = (const float*)d_in[8];
  const float* b2a = (const float*)d_in[9];
  const float* w2b = (const float*)d_in[10];
  const float* s2b = (const float*)d_in[11];
  const float* b2b = (const float*)d_in[12];
  const float* w3 = (const float*)d_in[13];
  const float* s3 = (const float*)d_in[14];
  const float* b3 = (const float*)d_in[15];
  const float* w4 = (const float*)d_in[16];
  const float* s4 = (const float*)d_in[17];
  const float* b4 = (const float*)d_in[18];
  const float* w5a = (const float*)d_in[19];
  const float* s5a = (const float*)d_in[20];
  const float* b5a = (const float*)d_in[21];
  const float* w5b = (const float*)d_in[22];
  const float* s5b = (const float*)d_in[23];
  const float* b5b = (const float*)d_in[24];
  const float* w6 = (const float*)d_in[25];
  float* out = (float*)d_out;

  char* wsp = (char*)d_ws;
  size_t off = 0;
  auto alloc = [&](size_t bytes) -> void* {
    void* p = wsp + off;
    off += (bytes + 255) & ~(size_t)255;
    return p;
  };
  int* idx1 = (int*)alloc((size_t)NBATCH * NPTS * KNN * 4);
  int* idx2 = (int*)alloc((size_t)NBATCH * NPTS * KNN * 4);
  int* idx3 = (int*)alloc((size_t)NBATCH * NPTS * KNN * 4);
  float* x1 = (float*)alloc((size_t)NBATCH * 64 * NPTS * 4);
  float* x2 = (float*)alloc((size_t)NBATCH * 64 * NPTS * 4);
  float* x3 = (float*)alloc((size_t)NBATCH * 64 * NPTS * 4);
  float* znbBuf = (float*)alloc((size_t)NBATCH * NPTS * 64 * 4);
  float* baseBuf = (float*)alloc((size_t)NBATCH * NPTS * 64 * 4);
  float* pmaxb = (float*)alloc((size_t)NBATCH * 1024 * 32 * 4);
  float* g = (float*)alloc((size_t)NBATCH * 1024 * 4);
  float* t5a = (float*)alloc((size_t)NBATCH * 512 * 4);

  // Workspace overflow would corrupt device memory (hang risk). Fail fast.
  if (off > ws_size) return;

  const int knnGrid = NBATCH * NPTS / 32;             // 512
  const int ecGrid = (NBATCH * NPTS + 11) / 12;       // 1366
  const int pcGrid = NBATCH * 32;                     // 256

  knn_kernel<3><<<knnGrid, 512, 0, stream>>>(x + 6 * NPTS, NPTS, 9 * NPTS, idx1);
  pointconv_kernel<9><<<pcGrid, 256, 0, stream>>>(x, 9 * NPTS, w1a, znbBuf, baseBuf);
  edge_kernel<true><<<ecGrid, 256, 0, stream>>>(znbBuf, baseBuf, idx1, s1a, b1a, w1b, s1b, b1b,
                                                x1);
  knn_kernel<64><<<knnGrid, 512, 0, stream>>>(x1, NPTS, 64 * NPTS, idx2);
  pointconv_kernel<64><<<pcGrid, 256, 0, stream>>>(x1, 64 * NPTS, w2a, znbBuf, baseBuf);
  edge_kernel<true><<<ecGrid, 256, 0, stream>>>(znbBuf, baseBuf, idx2, s2a, b2a, w2b, s2b, b2b,
                                                x2);
  knn_kernel<64><<<knnGrid, 512, 0, stream>>>(x2, NPTS, 64 * NPTS, idx3);
  pointconv_kernel<64><<<pcGrid, 256, 0, stream>>>(x2, 64 * NPTS, w3, znbBuf, baseBuf);
  edge_kernel<false><<<ecGrid, 256, 0, stream>>>(znbBuf, baseBuf, idx3, s3, b3, nullptr, nullptr,
                                                 nullptr, x3);
  x4max_kernel<<<8192, 256, 0, stream>>>(x1, x2, x3, w4, s4, b4, pmaxb);
  gmax_kernel<<<32, 256, 0, stream>>>(pmaxb, g);
  t5a_kernel<<<1024, 256, 0, stream>>>(g, w5a, t5a);
  head_kernel<<<256, 1024, 0, stream>>>(x1, x2, x3, t5a, w5a, s5a, b5a, w5b, s5b, b5b, w6, out);
}

// Round 22
// 1025.534 us; speedup vs baseline: 1.0416x; 1.0142x over previous
//
#include <hip/hip_runtime.h>
#include <cstddef>
#include <cstdint>

namespace {

constexpr int NBATCH = 8;
constexpr int NPTS = 2048;
constexpr int KNN = 20;

__device__ __forceinline__ float lrelu(float v) { return fmaxf(v, 0.2f * v); }

// ---------- KNN: top-20 neighbors by neg squared distance ----------
// Keys packed into positive doubles: bits = sortable32(dist)<<30 |
// (2047-idx)<<19 -> double order == (exact f32 dist, then smaller index);
// keys unique -> lax.top_k set semantics. Branch-free per-lane sorted top-20
// via the carry-free min/max identity (39 f64 ops, 2-op critical path).
// 512 threads: 8 waves x 4 rows (dot), 16 lanes/row x 128 cand (select).
template <int C>
__global__ __launch_bounds__(512) void knn_kernel(const float* __restrict__ x, int chStride,
                                                  int bStride, int* __restrict__ idxOut) {
  constexpr int CP = (C + 3) & ~3;   // padded channels
  constexpr int MT = 128;            // columns per tile
  constexpr int ROWS = 32;           // rows per block
  constexpr int RPW = 4;             // rows per wave (dot phase)
  constexpr int LPR = 16;            // lanes per row (select phase)
  constexpr int DS = MT + 4;         // dist row stride (132 -> 2-way, free)
  constexpr int NT = NPTS / MT;      // 16 tiles

  __shared__ float qt[ROWS * CP];
  __shared__ float xt[CP * MT];      // column-major: xt[c*MT + m]
  __shared__ float dist[ROWS * DS];

  const int tid = threadIdx.x;
  const int lane = tid & 63;
  const int wv = tid >> 6;           // 0..7
  const int r0 = wv * RPW;
  const int b = blockIdx.x / (NPTS / ROWS);
  const int n0 = (blockIdx.x % (NPTS / ROWS)) * ROWS;
  const float* xb = x + (size_t)b * bStride;

  for (int t = tid; t < ROWS * CP; t += 512) {
    int r = t / CP, c = t % CP;
    qt[r * CP + c] = (c < C) ? xb[(size_t)c * chStride + n0 + r] : 0.f;
  }
  __syncthreads();

  // per-row query self-dot (broadcast LDS reads)
  float xn[RPW];
#pragma unroll
  for (int r = 0; r < RPW; ++r) {
    float s = 0.f;
#pragma unroll
    for (int cb = 0; cb < CP; cb += 4) {
      float4 qv = *(const float4*)&qt[(r0 + r) * CP + cb];
      s = fmaf(qv.x, qv.x, s);
      s = fmaf(qv.y, qv.y, s);
      s = fmaf(qv.z, qv.z, s);
      s = fmaf(qv.w, qv.w, s);
    }
    xn[r] = s;
  }

  // selection state: 16 lanes/row, per-lane sorted-ascending top-20 keys
  const int srow = tid >> 4;         // 0..31
  const int ssub = tid & 15;
  double lv[KNN];
#pragma unroll
  for (int s = 0; s < KNN; ++s) lv[s] = -1.0;  // below all packed keys (>=0)

  // running index-key part: (2047 - gidx) << 19, gidx = mt*128 + j*16 + ssub
  unsigned long long ib = (unsigned long long)(2047 - ssub) << 19;

#pragma unroll 1
  for (int mt = 0; mt < NT; ++mt) {
    __syncthreads();  // all waves done reading xt of previous tile
    {
      const float4 z4 = make_float4(0.f, 0.f, 0.f, 0.f);
      for (int t = tid; t < CP * MT / 4; t += 512) {
        int f = t * 4;
        int c = f >> 7, m = f & (MT - 1);
        *(float4*)&xt[f] =
            (c < C) ? *(const float4*)&xb[(size_t)c * chStride + mt * MT + m] : z4;
      }
    }
    __syncthreads();  // xt ready

    float acc0[RPW], acc1[RPW];
    float xm0 = 0.f, xm1 = 0.f;
#pragma unroll
    for (int r = 0; r < RPW; ++r) { acc0[r] = 0.f; acc1[r] = 0.f; }
#pragma unroll 1
    for (int cb = 0; cb < CP; cb += 4) {
      float x00 = xt[(cb + 0) * MT + lane];
      float x01 = xt[(cb + 1) * MT + lane];
      float x02 = xt[(cb + 2) * MT + lane];
      float x03 = xt[(cb + 3) * MT + lane];
      float x10 = xt[(cb + 0) * MT + 64 + lane];
      float x11 = xt[(cb + 1) * MT + 64 + lane];
      float x12 = xt[(cb + 2) * MT + 64 + lane];
      float x13 = xt[(cb + 3) * MT + 64 + lane];
      xm0 = fmaf(x00, x00, xm0);
      xm0 = fmaf(x01, x01, xm0);
      xm0 = fmaf(x02, x02, xm0);
      xm0 = fmaf(x03, x03, xm0);
      xm1 = fmaf(x10, x10, xm1);
      xm1 = fmaf(x11, x11, xm1);
      xm1 = fmaf(x12, x12, xm1);
      xm1 = fmaf(x13, x13, xm1);
#pragma unroll
      for (int r = 0; r < RPW; ++r) {
        float4 qv = *(const float4*)&qt[(r0 + r) * CP + cb];
        acc0[r] = fmaf(qv.x, x00, acc0[r]);
        acc0[r] = fmaf(qv.y, x01, acc0[r]);
        acc0[r] = fmaf(qv.z, x02, acc0[r]);
        acc0[r] = fmaf(qv.w, x03, acc0[r]);
        acc1[r] = fmaf(qv.x, x10, acc1[r]);
        acc1[r] = fmaf(qv.y, x11, acc1[r]);
        acc1[r] = fmaf(qv.z, x12, acc1[r]);
        acc1[r] = fmaf(qv.w, x13, acc1[r]);
      }
    }
#pragma unroll
    for (int r = 0; r < RPW; ++r) {
      dist[(r0 + r) * DS + lane] = 2.f * acc0[r] - xn[r] - xm0;
      dist[(r0 + r) * DS + 64 + lane] = 2.f * acc1[r] - xn[r] - xm1;
    }
    // rows r0..r0+3 are read below by lanes of this same wave -> no barrier

    // per-lane: pack candidate into key, branch-free sorted insert
#pragma unroll
    for (int j = 0; j < MT / LPR; ++j) {
      float val = dist[srow * DS + j * LPR + ssub];
      unsigned int u = __float_as_uint(val);
      u ^= (unsigned int)(((int)u) >> 31) | 0x80000000u;
      double kd = __longlong_as_double((long long)(((unsigned long long)u << 30) | ib));
      ib -= (unsigned long long)LPR << 19;
#pragma unroll
      for (int s = 0; s < KNN - 1; ++s) lv[s] = fmin(lv[s + 1], fmax(lv[s], kd));
      lv[KNN - 1] = fmax(lv[KNN - 1], kd);
    }
  }

  // merge 16 lanes' lists per row: keys unique -> single-owner pop per round
  int* op = idxOut + ((size_t)b * NPTS + n0 + srow) * KNN;
#pragma unroll 1
  for (int round = 0; round < KNN; ++round) {
    double bv = lv[KNN - 1];
    bv = fmax(bv, __shfl_xor(bv, 1));
    bv = fmax(bv, __shfl_xor(bv, 2));
    bv = fmax(bv, __shfl_xor(bv, 4));
    bv = fmax(bv, __shfl_xor(bv, 8));
    if (lv[KNN - 1] == bv) {  // exactly one lane per row owns the winner
#pragma unroll
      for (int s = KNN - 1; s > 0; --s) lv[s] = lv[s - 1];
      lv[0] = -1.0;
    }
    if (ssub == 0)
      op[round] =
          2047 - (int)((unsigned long long)(__double_as_longlong(bv) >> 19) & 0x7FFull);
  }
}

// ---------- per-point conv1 factoring ----------
template <int C>
__global__ __launch_bounds__(256) __attribute__((amdgpu_waves_per_eu(4, 4))) void
pointconv_kernel(const float* __restrict__ x, int bStride, const float* __restrict__ W,
                 float* __restrict__ znb, float* __restrict__ base) {
  const int blk = blockIdx.x;
  const int b = blk >> 5;
  const int nc = blk & 31;
  const int nl = threadIdx.x & 63;
  const int q = __builtin_amdgcn_readfirstlane(threadIdx.x >> 6);  // 0..3
  const int n = nc * 64 + nl;
  const float* xb = x + (size_t)b * bStride;

  float fz[16], fb[16];
#pragma unroll
  for (int t = 0; t < 16; ++t) { fz[t] = 0.f; fb[t] = 0.f; }
#pragma unroll 4
  for (int c = 0; c < C; ++c) {
    float xv = xb[(size_t)c * NPTS + n];
#pragma unroll
    for (int t = 0; t < 16; ++t) {
      float w0 = W[(q * 16 + t) * 2 * C + c];
      float w1 = W[(q * 16 + t) * 2 * C + C + c];
      fz[t] = fmaf(w0, xv, fz[t]);
      fb[t] = fmaf(w1 - w0, xv, fb[t]);
    }
  }
  const size_t o0 = ((size_t)(b * NPTS + n)) * 64 + q * 16;
#pragma unroll
  for (int t = 0; t < 16; t += 4)
    *(float4*)&znb[o0 + t] = make_float4(fz[t], fz[t + 1], fz[t + 2], fz[t + 3]);
#pragma unroll
  for (int t = 0; t < 16; t += 4)
    *(float4*)&base[o0 + t] = make_float4(fb[t], fb[t + 1], fb[t + 2], fb[t + 3]);
}

// ---------- fused edge kernel ----------
template <bool TWO>
__global__ __launch_bounds__(256) __attribute__((amdgpu_waves_per_eu(2, 4))) void edge_kernel(
    const float* __restrict__ znb, const float* __restrict__ base,
    const int* __restrict__ idx, const float* __restrict__ s1, const float* __restrict__ b1,
    const float* __restrict__ W2, const float* __restrict__ s2, const float* __restrict__ b2,
    float* __restrict__ xout) {
  __shared__ float baseS[12][64];
  const int tid = threadIdx.x;
  const int gp0 = blockIdx.x * 12;

  for (int t = tid; t < 12 * 64; t += 256) {
    int p = t >> 6, cp = t & 63;
    int gpt = gp0 + p;
    baseS[p][cp] = (gpt < NBATCH * NPTS) ? base[(size_t)gpt * 64 + cp] : 0.f;
  }
  __syncthreads();

  const int lane = tid & 63;
  const int wv = __builtin_amdgcn_readfirstlane(tid >> 6);
  int p = lane / 20;
  const int k = lane - p * 20;
  const bool pact = (p < 3);
  if (!pact) p = 2;
  const int pl = wv * 3 + p;
  const int gpt = gp0 + pl;
  const bool act = pact && (gpt < NBATCH * NPTS);
  const int gptc = (gpt < NBATCH * NPTS) ? gpt : (NBATCH * NPTS - 1);
  const int bb = gptc >> 11;
  const int nn = gptc & (NPTS - 1);
  const int m = idx[(size_t)gptc * KNN + k];
  const float* zg = znb + ((size_t)bb * NPTS + m) * 64;

  float y1[64];
#pragma unroll
  for (int c4 = 0; c4 < 64; c4 += 4) {
    float4 zv = *(const float4*)&zg[c4];
    float4 bv = *(const float4*)&baseS[pl][c4];
    y1[c4 + 0] = zv.x + bv.x;
    y1[c4 + 1] = zv.y + bv.y;
    y1[c4 + 2] = zv.z + bv.z;
    y1[c4 + 3] = zv.w + bv.w;
  }
#pragma unroll
  for (int cp = 0; cp < 64; ++cp) y1[cp] = lrelu(fmaf(y1[cp], s1[cp], b1[cp]));

  if constexpr (TWO) {
#pragma unroll 2
    for (int o2 = 0; o2 < 64; ++o2) {
      float a = 0.f;
#pragma unroll
      for (int c = 0; c < 64; ++c) a = fmaf(W2[o2 * 64 + c], y1[c], a);
      float z = lrelu(fmaf(a, s2[o2], b2[o2]));
#pragma unroll
      for (int off = 1; off < 32; off <<= 1) {
        float ov = __shfl_down(z, off);
        if (k + off < KNN) z = fmaxf(z, ov);
      }
      if (act && k == 0) xout[((size_t)bb * 64 + o2) * NPTS + nn] = z;
    }
  } else {
#pragma unroll 2
    for (int o2 = 0; o2 < 64; ++o2) {
      float z = y1[o2];
#pragma unroll
      for (int off = 1; off < 32; off <<= 1) {
        float ov = __shfl_down(z, off);
        if (k + off < KNN) z = fmaxf(z, ov);
      }
      if (act && k == 0) xout[((size_t)bb * 64 + o2) * NPTS + nn] = z;
    }
  }
}

// ---------- x4 = lrelu(s4*(W4·[x1;x2;x3])+b4), partial max ----------
__global__ __launch_bounds__(256) void x4max_kernel(const float* __restrict__ x1,
                                                    const float* __restrict__ x2,
                                                    const float* __restrict__ x3,
                                                    const float* __restrict__ W4,
                                                    const float* __restrict__ s4,
                                                    const float* __restrict__ b4,
                                                    float* __restrict__ pmax) {
  const int blk = blockIdx.x;
  const int b = blk >> 10;
  const int oc = (blk >> 5) & 31;
  const int nc = blk & 31;
  const int nl = threadIdx.x & 63;
  const int q = __builtin_amdgcn_readfirstlane(threadIdx.x >> 6);  // 0..3
  const int n = nc * 64 + nl;
  const float* xA = x1 + (size_t)b * 64 * NPTS;
  const float* xB = x2 + (size_t)b * 64 * NPTS;
  const float* xC = x3 + (size_t)b * 64 * NPTS;
  const float* wq = W4 + (size_t)(oc * 32 + q * 8) * 192;

  float f[8];
#pragma unroll
  for (int t = 0; t < 8; ++t) f[t] = 0.f;
#pragma unroll 2
  for (int cb = 0; cb < 64; cb += 4) {
    float xv0 = xA[(size_t)(cb + 0) * NPTS + n];
    float xv1 = xA[(size_t)(cb + 1) * NPTS + n];
    float xv2 = xA[(size_t)(cb + 2) * NPTS + n];
    float xv3 = xA[(size_t)(cb + 3) * NPTS + n];
#pragma unroll
    for (int t = 0; t < 8; ++t) {
      float4 wv = *(const float4*)&wq[(size_t)t * 192 + cb];
      f[t] = fmaf(wv.x, xv0, f[t]);
      f[t] = fmaf(wv.y, xv1, f[t]);
      f[t] = fmaf(wv.z, xv2, f[t]);
      f[t] = fmaf(wv.w, xv3, f[t]);
    }
  }
#pragma unroll 2
  for (int cb = 0; cb < 64; cb += 4) {
    float xv0 = xB[(size_t)(cb + 0) * NPTS + n];
    float xv1 = xB[(size_t)(cb + 1) * NPTS + n];
    float xv2 = xB[(size_t)(cb + 2) * NPTS + n];
    float xv3 = xB[(size_t)(cb + 3) * NPTS + n];
#pragma unroll
    for (int t = 0; t < 8; ++t) {
      float4 wv = *(const float4*)&wq[(size_t)t * 192 + 64 + cb];
      f[t] = fmaf(wv.x, xv0, f[t]);
      f[t] = fmaf(wv.y, xv1, f[t]);
      f[t] = fmaf(wv.z, xv2, f[t]);
      f[t] = fmaf(wv.w, xv3, f[t]);
    }
  }
#pragma unroll 2
  for (int cb = 0; cb < 64; cb += 4) {
    float xv0 = xC[(size_t)(cb + 0) * NPTS + n];
    float xv1 = xC[(size_t)(cb + 1) * NPTS + n];
    float xv2 = xC[(size_t)(cb + 2) * NPTS + n];
    float xv3 = xC[(size_t)(cb + 3) * NPTS + n];
#pragma unroll
    for (int t = 0; t < 8; ++t) {
      float4 wv = *(const float4*)&wq[(size_t)t * 192 + 128 + cb];
      f[t] = fmaf(wv.x, xv0, f[t]);
      f[t] = fmaf(wv.y, xv1, f[t]);
      f[t] = fmaf(wv.z, xv2, f[t]);
      f[t] = fmaf(wv.w, xv3, f[t]);
    }
  }
#pragma unroll
  for (int t = 0; t < 8; ++t) {
    const int o = oc * 32 + q * 8 + t;
    float v = lrelu(fmaf(f[t], s4[o], b4[o]));
#pragma unroll
    for (int off = 32; off; off >>= 1) v = fmaxf(v, __shfl_down(v, off));
    if (nl == 0) pmax[(size_t)(b * 1024 + o) * 32 + nc] = v;
  }
}

__global__ __launch_bounds__(256) void gmax_kernel(const float* __restrict__ pmax,
                                                   float* __restrict__ g) {
  int i = blockIdx.x * 256 + threadIdx.x;
  if (i >= NBATCH * 1024) return;
  float v = -__builtin_inff();
#pragma unroll
  for (int j = 0; j < 32; ++j) v = fmaxf(v, pmax[(size_t)i * 32 + j]);
  g[i] = v;
}

__global__ __launch_bounds__(256) void t5a_kernel(const float* __restrict__ g,
                                                  const float* __restrict__ w5a,
                                                  float* __restrict__ t5a) {
  const int task = blockIdx.x * 4 + (threadIdx.x >> 6);  // 0..4095
  const int lane = threadIdx.x & 63;
  const int b = task >> 9;
  const int o5 = task & 511;
  float acc = 0.f;
  for (int c = lane; c < 1024; c += 64) acc = fmaf(w5a[(size_t)o5 * 1216 + c], g[b * 1024 + c], acc);
#pragma unroll
  for (int off = 32; off; off >>= 1) acc += __shfl_down(acc, off);
  if (lane == 0) t5a[task] = acc;
}

// ---------- head: a(512) -> h2(256) -> out(13), per 64-column tile ----------
// LDS (80KB) caps occupancy at 1 block/CU = 4 waves/EU; waves_per_eu(4,4)
// aligns the register budget (128) with that cap. (Best measured config:
// double-buffered als, unroll 4/2 -- deeper unrolls and LDS-shrink both
// regressed in R20/R21.)
__global__ __launch_bounds__(1024) __attribute__((amdgpu_waves_per_eu(4, 4))) void head_kernel(
    const float* __restrict__ x1, const float* __restrict__ x2, const float* __restrict__ x3,
    const float* __restrict__ t5a, const float* __restrict__ w5a, const float* __restrict__ s5a,
    const float* __restrict__ b5a, const float* __restrict__ w5b, const float* __restrict__ s5b,
    const float* __restrict__ b5b, const float* __restrict__ w6, float* __restrict__ out) {
  __shared__ float xls[192 * 64];
  __shared__ float als[2][64 * 64];
  const int tid = threadIdx.x;
  const int nl = tid & 63;
  const int q = __builtin_amdgcn_readfirstlane(tid >> 6);  // 0..15
  const int blk = blockIdx.x;
  const int b = blk >> 5;
  const int n0 = (blk & 31) * 64;

  for (int t = tid; t < 192 * 64; t += 1024) {
    int c = t >> 6, j = t & 63;
    const float* xp = (c < 64) ? x1 : ((c < 128) ? x2 : x3);
    xls[t] = xp[((size_t)b * 64 + (c & 63)) * NPTS + n0 + j];
  }
  __syncthreads();

  float h2[16];
#pragma unroll
  for (int t = 0; t < 16; ++t) h2[t] = 0.f;

#pragma unroll 1
  for (int ch = 0; ch < 8; ++ch) {
    float a[4];
#pragma unroll
    for (int t = 0; t < 4; ++t) a[t] = t5a[b * 512 + ch * 64 + q + 16 * t];
#pragma unroll 4
    for (int cb = 0; cb < 192; cb += 4) {
      float xv0 = xls[(cb + 0) * 64 + nl];
      float xv1 = xls[(cb + 1) * 64 + nl];
      float xv2 = xls[(cb + 2) * 64 + nl];
      float xv3 = xls[(cb + 3) * 64 + nl];
#pragma unroll
      for (int t = 0; t < 4; ++t) {
        float4 wv = *(const float4*)&w5a[(size_t)(ch * 64 + q + 16 * t) * 1216 + 1024 + cb];
        a[t] = fmaf(wv.x, xv0, a[t]);
        a[t] = fmaf(wv.y, xv1, a[t]);
        a[t] = fmaf(wv.z, xv2, a[t]);
        a[t] = fmaf(wv.w, xv3, a[t]);
      }
    }
    float* alsb = als[ch & 1];
#pragma unroll
    for (int t = 0; t < 4; ++t) {
      const int oa = ch * 64 + q + 16 * t;
      alsb[(q + 16 * t) * 64 + nl] = lrelu(fmaf(a[t], s5a[oa], b5a[oa]));
    }
    __syncthreads();  // alsb fully written; prior-parity reads done 1 chunk ago
#pragma unroll 2
    for (int ca = 0; ca < 64; ca += 4) {
      float av0 = alsb[(ca + 0) * 64 + nl];
      float av1 = alsb[(ca + 1) * 64 + nl];
      float av2 = alsb[(ca + 2) * 64 + nl];
      float av3 = alsb[(ca + 3) * 64 + nl];
#pragma unroll
      for (int t = 0; t < 16; ++t) {
        float4 wv = *(const float4*)&w5b[(size_t)(q + 16 * t) * 512 + ch * 64 + ca];
        h2[t] = fmaf(wv.x, av0, h2[t]);
        h2[t] = fmaf(wv.y, av1, h2[t]);
        h2[t] = fmaf(wv.z, av2, h2[t]);
        h2[t] = fmaf(wv.w, av3, h2[t]);
      }
    }
  }
#pragma unroll
  for (int t = 0; t < 16; ++t) {
    const int o2 = q + 16 * t;
    h2[t] = lrelu(fmaf(h2[t], s5b[o2], b5b[o2]));
  }
  float pq[13];
#pragma unroll
  for (int o = 0; o < 13; ++o) {
    float s = 0.f;
#pragma unroll
    for (int t = 0; t < 16; ++t) s = fmaf(w6[o * 256 + q + 16 * t], h2[t], s);
    pq[o] = s;
  }
  // reduce 16 wave-partials -> 8 (waves 8..15 add into 0..7's slots), then tree
  __syncthreads();  // xls reads all done; safe to overwrite
  if (q < 8) {
#pragma unroll
    for (int o = 0; o < 13; ++o) xls[(q * 13 + o) * 64 + nl] = pq[o];
  }
  __syncthreads();
  if (q >= 8) {
#pragma unroll
    for (int o = 0; o < 13; ++o) xls[((q - 8) * 13 + o) * 64 + nl] += pq[o];
  }
  __syncthreads();
  for (int t = tid; t < 13 * 64; t += 1024) {
    int o = t >> 6, j = t & 63;
    float s = 0.f;
#pragma unroll
    for (int qq = 0; qq < 8; ++qq) s += xls[(qq * 13 + o) * 64 + j];
    out[((size_t)b * 13 + o) * NPTS + n0 + j] = s;
  }
}

}  // namespace

extern "C" void kernel_launch(void* const* d_in, const int* in_sizes, int n_in, void* d_out,
                              int out_size, void* d_ws, size_t ws_size, hipStream_t stream) {
  (void)in_sizes; (void)n_in; (void)out_size;
  const float* x = (const float*)d_in[0];
  const float* w1a = (const float*)d_in[1];
  const float* s1a = (const float*)d_in[2];
  const float* b1a = (const float*)d_in[3];
  const float* w1b = (const float*)d_in[4];
  const float* s1b = (const float*)d_in[5];
  const float* b1b = (const float*)d_in[6];
  const float* w2a = (const float*)d_in[7];
  const float* s2a = (const float*)d_in[8];
  const float* b2a = (const float*)d_in[9];
  const float* w2b = (const float*)d_in[10];
  const float* s2b = (const float*)d_in[11];
  const float* b2b = (const float*)d_in[12];
  const float* w3 = (const float*)d_in[13];
  const float* s3 = (const float*)d_in[14];
  const float* b3 = (const float*)d_in[15];
  const float* w4 = (const float*)d_in[16];
  const float* s4 = (const float*)d_in[17];
  const float* b4 = (const float*)d_in[18];
  const float* w5a = (const float*)d_in[19];
  const float* s5a = (const float*)d_in[20];
  const float* b5a = (const float*)d_in[21];
  const float* w5b = (const float*)d_in[22];
  const float* s5b = (const float*)d_in[23];
  const float* b5b = (const float*)d_in[24];
  const float* w6 = (const float*)d_in[25];
  float* out = (float*)d_out;

  char* wsp = (char*)d_ws;
  size_t off = 0;
  auto alloc = [&](size_t bytes) -> void* {
    void* p = wsp + off;
    off += (bytes + 255) & ~(size_t)255;
    return p;
  };
  int* idx1 = (int*)alloc((size_t)NBATCH * NPTS * KNN * 4);
  int* idx2 = (int*)alloc((size_t)NBATCH * NPTS * KNN * 4);
  int* idx3 = (int*)alloc((size_t)NBATCH * NPTS * KNN * 4);
  float* x1 = (float*)alloc((size_t)NBATCH * 64 * NPTS * 4);
  float* x2 = (float*)alloc((size_t)NBATCH * 64 * NPTS * 4);
  float* x3 = (float*)alloc((size_t)NBATCH * 64 * NPTS * 4);
  float* znbBuf = (float*)alloc((size_t)NBATCH * NPTS * 64 * 4);
  float* baseBuf = (float*)alloc((size_t)NBATCH * NPTS * 64 * 4);
  float* pmaxb = (float*)alloc((size_t)NBATCH * 1024 * 32 * 4);
  float* g = (float*)alloc((size_t)NBATCH * 1024 * 4);
  float* t5a = (float*)alloc((size_t)NBATCH * 512 * 4);

  // Workspace overflow would corrupt device memory (hang risk). Fail fast.
  if (off > ws_size) return;

  const int knnGrid = NBATCH * NPTS / 32;             // 512
  const int ecGrid = (NBATCH * NPTS + 11) / 12;       // 1366
  const int pcGrid = NBATCH * 32;                     // 256

  knn_kernel<3><<<knnGrid, 512, 0, stream>>>(x + 6 * NPTS, NPTS, 9 * NPTS, idx1);
  pointconv_kernel<9><<<pcGrid, 256, 0, stream>>>(x, 9 * NPTS, w1a, znbBuf, baseBuf);
  edge_kernel<true><<<ecGrid, 256, 0, stream>>>(znbBuf, baseBuf, idx1, s1a, b1a, w1b, s1b, b1b,
                                                x1);
  knn_kernel<64><<<knnGrid, 512, 0, stream>>>(x1, NPTS, 64 * NPTS, idx2);
  pointconv_kernel<64><<<pcGrid, 256, 0, stream>>>(x1, 64 * NPTS, w2a, znbBuf, baseBuf);
  edge_kernel<true><<<ecGrid, 256, 0, stream>>>(znbBuf, baseBuf, idx2, s2a, b2a, w2b, s2b, b2b,
                                                x2);
  knn_kernel<64><<<knnGrid, 512, 0, stream>>>(x2, NPTS, 64 * NPTS, idx3);
  pointconv_kernel<64><<<pcGrid, 256, 0, stream>>>(x2, 64 * NPTS, w3, znbBuf, baseBuf);
  edge_kernel<false><<<ecGrid, 256, 0, stream>>>(znbBuf, baseBuf, idx3, s3, b3, nullptr, nullptr,
                                                 nullptr, x3);
  x4max_kernel<<<8192, 256, 0, stream>>>(x1, x2, x3, w4, s4, b4, pmaxb);
  gmax_kernel<<<32, 256, 0, stream>>>(pmaxb, g);
  t5a_kernel<<<1024, 256, 0, stream>>>(g, w5a, t5a);
  head_kernel<<<256, 1024, 0, stream>>>(x1, x2, x3, t5a, w5a, s5a, b5a, w5b, s5b, b5b, w6, out);
}